// Round 6
// baseline (8264.923 us; speedup 1.0000x reference)
//
#include <hip/hip_runtime.h>

#define N 4096
#define IN_DIM 128
#define T_STEPS 2048
#define KSLOTS 576           // uniform padded ELL row width; max nnz ~490 (mean 409.6, sd 19.2)
#define CHUNKS (KSLOTS / 64) // 9, uniform for all rows
#define NBLOCKS 64
#define NTHREADS 1024
#define ROWS_PER_WAVE 4
#define ROWS_PER_BLOCK (ROWS_PER_WAVE * (NTHREADS / 64))   // 64
#define SENTINEL_BITS 0x7FC00001u   // qNaN; h is always finite -> producers never write this

typedef float f32x4 __attribute__((ext_vector_type(4)));

// ---------------------------------------------------------------------------
// Kernel 0: fill out with the sentinel, write-through (agent scope) so it is
// at the coherence point before any step-kernel poll. Defends against 0xAA
// poison and stale floats from a previous replay (both non-sentinel).
// ---------------------------------------------------------------------------
__global__ void init_sentinel(float* __restrict__ out) {
    const size_t i = (size_t)blockIdx.x * blockDim.x + threadIdx.x;
    __hip_atomic_store(&out[i], __uint_as_float(SENTINEL_BITS),
                       __ATOMIC_RELAXED, __HIP_MEMORY_SCOPE_AGENT);
}

// ---------------------------------------------------------------------------
// Kernel 1: dense W -> uniform padded ELL with bank-aware chunk assignment
// (each 64-slot chunk hits every LDS bank ~2x; 2-way is free on gfx950).
// Padding: val=0, col=0 (same-address broadcast, free).
// ---------------------------------------------------------------------------
__global__ void build_ell(const float* __restrict__ W,
                          float* __restrict__ vals,
                          unsigned short* __restrict__ cols) {
    __shared__ float sval[KSLOTS];
    __shared__ unsigned short scol[KSLOTS];
    __shared__ float slot_val[KSLOTS];
    __shared__ unsigned short slot_col[KSLOTS];
    __shared__ int chunk_fill[CHUNKS];
    __shared__ int cnt;

    const int r = blockIdx.x;
    const int tid = threadIdx.x;
    if (tid == 0) cnt = 0;
    if (tid < CHUNKS) chunk_fill[tid] = 0;
    __syncthreads();

    const float* wrow = W + (size_t)r * N;
    for (int j = tid; j < N; j += blockDim.x) {
        float w = wrow[j];
        if (w != 0.0f) {
            int p = atomicAdd(&cnt, 1);
            if (p < KSLOTS) { sval[p] = w; scol[p] = (unsigned short)j; }
        }
    }
    __syncthreads();
    for (int j = tid; j < KSLOTS; j += blockDim.x) { slot_val[j] = 0.0f; slot_col[j] = 0; }
    __syncthreads();

    if (tid < 32) {  // one thread per bank spreads its entries across chunks
        int k = 0;
        const int n = (cnt < KSLOTS) ? cnt : KSLOTS;
        for (int p = 0; p < n; ++p) {
            int c = scol[p];
            if ((c & 31) == tid) {
                int ch0 = (k + tid) % CHUNKS;
                for (int probe = 0; probe < CHUNKS; ++probe) {
                    int cc = ch0 + probe; if (cc >= CHUNKS) cc -= CHUNKS;
                    int pos = atomicAdd(&chunk_fill[cc], 1);
                    if (pos < 64) {
                        slot_val[cc * 64 + pos] = sval[p];
                        slot_col[cc * 64 + pos] = (unsigned short)c;
                        break;
                    }
                }
                ++k;
            }
        }
    }
    __syncthreads();

    float* vrow = vals + (size_t)r * KSLOTS;
    unsigned short* crow = cols + (size_t)r * KSLOTS;
    for (int j = tid; j < KSLOTS; j += blockDim.x) { vrow[j] = slot_val[j]; crow[j] = slot_col[j]; }
}

// ---------------------------------------------------------------------------
// Coherent 16B load straight from the coherence point (bypasses L1+L2).
// ---------------------------------------------------------------------------
__device__ __forceinline__ f32x4 load_coherent_x4(const float* p) {
    f32x4 v;
    asm volatile("global_load_dwordx4 %0, %1, off sc0 sc1\n\t"
                 "s_waitcnt vmcnt(0)"
                 : "=v"(v) : "v"(p) : "memory");
    return v;
}

// ---------------------------------------------------------------------------
// Kernel 2: persistent step kernel, barrier-free (data-as-flag), 64 blocks x
// 1024 threads, 4 rows/wave (64 rows/block).
//  - full ELL slice register-hoisted (36 vals + 16 packed col-pairs + 4
//    singles): ZERO weight traffic inside the t-loop.
//  - double-buffered h/x LDS -> ONE __syncthreads per step. Safety: between
//    consecutive barriers, waves write only buf[t&1] while laggards read
//    buf[(t-1)&1]; a wave reaching stage(t+2) has passed barrier(t+1), which
//    required every wave to finish gather(t) -> no overwrite hazard.
//  - consumers poll out[t-1] with coherent dwordx4; producers store via the
//    proven scalar write-through atomic path (lanes 0-3 in parallel).
//  - skew self-limits at 1 step; each block writes only its own 64 rows.
// ---------------------------------------------------------------------------
__global__ void __launch_bounds__(NTHREADS, 1) esn_steps(
    const float* __restrict__ x,
    const float* __restrict__ W_in,
    const float* __restrict__ vals,
    const unsigned short* __restrict__ cols,
    float* __restrict__ out) {

    __shared__ float hbuf[2][N];        // 2 x 16 KB
    __shared__ float xbuf[2][IN_DIM];

    const int tid  = threadIdx.x;
    const int lane = tid & 63;
    const int wave = tid >> 6;
    const int base = blockIdx.x * ROWS_PER_BLOCK + wave * ROWS_PER_WAVE;

    // Per-row W_in slices (8 regs).
    float w0[ROWS_PER_WAVE], w1[ROWS_PER_WAVE];
    #pragma unroll
    for (int j = 0; j < ROWS_PER_WAVE; ++j) {
        w0[j] = W_in[(base + j) * IN_DIM + lane];
        w1[j] = W_in[(base + j) * IN_DIM + 64 + lane];
    }

    // Hoist the 4-row ELL slice: 36 vals (f32) + per row 4 packed col-pairs
    // and 1 single col (byte offsets).
    float    rv[ROWS_PER_WAVE][CHUNKS];
    unsigned pk[ROWS_PER_WAVE][4];   // (c[2i]<<2) | (c[2i+1]<<2)<<16
    int      rc8[ROWS_PER_WAVE];
    #pragma unroll
    for (int j = 0; j < ROWS_PER_WAVE; ++j) {
        const float* vp = vals + (size_t)(base + j) * KSLOTS;
        const unsigned short* cp = cols + (size_t)(base + j) * KSLOTS;
        #pragma unroll
        for (int i = 0; i < CHUNKS; ++i) rv[j][i] = vp[(i << 6) + lane];
        #pragma unroll
        for (int i = 0; i < 4; ++i) {
            unsigned c0 = ((unsigned)cp[((2 * i) << 6) + lane]) << 2;
            unsigned c1 = ((unsigned)cp[((2 * i + 1) << 6) + lane]) << 2;
            pk[j][i] = c0 | (c1 << 16);
        }
        rc8[j] = ((int)cp[(8 << 6) + lane]) << 2;
    }

    const int i4 = tid << 2;

    for (int t = 0; t < T_STEPS; ++t) {
        const int cur = t & 1;
        float* __restrict__ hc = hbuf[cur];
        float* __restrict__ xc = xbuf[cur];

        // ---- stage x_t ----
        if (tid < IN_DIM) xc[tid] = x[t * IN_DIM + tid];

        // ---- stage h_{t-1}: coherent dwordx4 poll until sentinel gone ----
        f32x4 hv;
        if (t > 0) {
            const float* addr = out + (size_t)(t - 1) * N + i4;
            for (;;) {
                hv = load_coherent_x4(addr);
                bool not_ready = (__float_as_uint(hv.x) == SENTINEL_BITS) |
                                 (__float_as_uint(hv.y) == SENTINEL_BITS) |
                                 (__float_as_uint(hv.z) == SENTINEL_BITS) |
                                 (__float_as_uint(hv.w) == SENTINEL_BITS);
                if (!not_ready) break;
                __builtin_amdgcn_s_sleep(1);
            }
        } else {
            hv = (f32x4)(0.0f);
        }
        ((f32x4*)hc)[tid] = hv;
        __syncthreads();   // the ONLY barrier per step (double-buffer safety)

        // ---- 4 row dots: input part + register-ELL sparse gather ----
        float acc[ROWS_PER_WAVE];
        const float xa = xc[lane], xb = xc[64 + lane];
        #pragma unroll
        for (int j = 0; j < ROWS_PER_WAVE; ++j) acc[j] = w0[j] * xa + w1[j] * xb;

        #pragma unroll
        for (int j = 0; j < ROWS_PER_WAVE; ++j) {
            #pragma unroll
            for (int i = 0; i < 4; ++i) {
                unsigned p = pk[j][i];
                acc[j] += rv[j][2 * i]     * *(const float*)((const char*)hc + (p & 0xFFFFu));
                acc[j] += rv[j][2 * i + 1] * *(const float*)((const char*)hc + (p >> 16));
            }
            acc[j] += rv[j][8] * *(const float*)((const char*)hc + rc8[j]);
        }

        // butterfly reduce each acc[j] across the wave (all lanes get sums)
        #pragma unroll
        for (int j = 0; j < ROWS_PER_WAVE; ++j) {
            #pragma unroll
            for (int off = 32; off > 0; off >>= 1)
                acc[j] += __shfl_xor(acc[j], off);
        }

        // lanes 0..3 each finalize + store one row (parallel tanh + store)
        if (lane < ROWS_PER_WAVE) {
            float a = (lane == 0) ? acc[0] : (lane == 1) ? acc[1]
                    : (lane == 2) ? acc[2] : acc[3];
            float hp = hc[base + lane];
            float hn = 0.7f * hp + 0.3f * tanhf(a);
            __hip_atomic_store(&out[(size_t)t * N + base + lane], hn,
                               __ATOMIC_RELAXED, __HIP_MEMORY_SCOPE_AGENT);
        }
        // no trailing barrier: next stage writes the OTHER buffer
    }
}

// ---------------------------------------------------------------------------
// Workspace layout (bytes):
//   [0, +N*KSLOTS*4)       ELL vals (f32)   9.44 MB
//   [.., +N*KSLOTS*2)      ELL cols (u16)   4.72 MB
// ---------------------------------------------------------------------------
extern "C" void kernel_launch(void* const* d_in, const int* in_sizes, int n_in,
                              void* d_out, int out_size, void* d_ws, size_t ws_size,
                              hipStream_t stream) {
    const float* x    = (const float*)d_in[0];  // [2048,128]
    const float* W_in = (const float*)d_in[1];  // [4096,128]
    const float* W    = (const float*)d_in[2];  // [4096,4096]
    float* out = (float*)d_out;                 // [2048,4096]

    char* ws = (char*)d_ws;
    float* vals = (float*)ws;
    unsigned short* cols = (unsigned short*)(ws + (size_t)N * KSLOTS * 4);

    init_sentinel<<<(T_STEPS * N) / NTHREADS, NTHREADS, 0, stream>>>(out);
    build_ell<<<N, 256, 0, stream>>>(W, vals, cols);

    void* args[] = {(void*)&x, (void*)&W_in, (void*)&vals, (void*)&cols, (void*)&out};
    hipLaunchCooperativeKernel((void*)esn_steps, dim3(NBLOCKS), dim3(NTHREADS),
                               args, 0, stream);
}

// Round 10
// 7587.141 us; speedup vs baseline: 1.0893x; 1.0893x over previous
//
#include <hip/hip_runtime.h>

#define N 4096
#define IN_DIM 128
#define T_STEPS 2048
#define KSLOTS 576           // uniform padded ELL row width; max nnz ~490 (mean 409.6, sd 19.2)
#define CHUNKS (KSLOTS / 64) // 9, uniform for all rows
#define NBLOCKS 256
#define NTHREADS 1024
#define WAVES_PER_BLOCK (NTHREADS / 64)
#define SENTINEL_BITS 0x7FC00001u   // qNaN; h is always finite -> producers never write this

typedef float f32x4 __attribute__((ext_vector_type(4)));

// ---------------------------------------------------------------------------
// Kernel 0: fill out with the sentinel, write-through (agent scope) so it is
// at the coherence point before any step-kernel poll. Defends against 0xAA
// poison and stale floats from a previous replay (both non-sentinel).
// ---------------------------------------------------------------------------
__global__ void init_sentinel(float* __restrict__ out) {
    const size_t i = (size_t)blockIdx.x * blockDim.x + threadIdx.x;
    __hip_atomic_store(&out[i], __uint_as_float(SENTINEL_BITS),
                       __ATOMIC_RELAXED, __HIP_MEMORY_SCOPE_AGENT);
}

// ---------------------------------------------------------------------------
// Kernel 1: dense W -> uniform padded ELL with bank-aware chunk assignment
// (each 64-slot chunk hits every LDS bank ~2x; 2-way is free on gfx950).
// Padding: val=0, col=0 (same-address broadcast, free). Unchanged since R2.
// ---------------------------------------------------------------------------
__global__ void build_ell(const float* __restrict__ W,
                          float* __restrict__ vals,
                          unsigned short* __restrict__ cols) {
    __shared__ float sval[KSLOTS];
    __shared__ unsigned short scol[KSLOTS];
    __shared__ float slot_val[KSLOTS];
    __shared__ unsigned short slot_col[KSLOTS];
    __shared__ int chunk_fill[CHUNKS];
    __shared__ int cnt;

    const int r = blockIdx.x;
    const int tid = threadIdx.x;
    if (tid == 0) cnt = 0;
    if (tid < CHUNKS) chunk_fill[tid] = 0;
    __syncthreads();

    const float* wrow = W + (size_t)r * N;
    for (int j = tid; j < N; j += blockDim.x) {
        float w = wrow[j];
        if (w != 0.0f) {
            int p = atomicAdd(&cnt, 1);
            if (p < KSLOTS) { sval[p] = w; scol[p] = (unsigned short)j; }
        }
    }
    __syncthreads();
    for (int j = tid; j < KSLOTS; j += blockDim.x) { slot_val[j] = 0.0f; slot_col[j] = 0; }
    __syncthreads();

    if (tid < 32) {  // one thread per bank spreads its entries across chunks
        int k = 0;
        const int n = (cnt < KSLOTS) ? cnt : KSLOTS;
        for (int p = 0; p < n; ++p) {
            int c = scol[p];
            if ((c & 31) == tid) {
                int ch0 = (k + tid) % CHUNKS;
                for (int probe = 0; probe < CHUNKS; ++probe) {
                    int cc = ch0 + probe; if (cc >= CHUNKS) cc -= CHUNKS;
                    int pos = atomicAdd(&chunk_fill[cc], 1);
                    if (pos < 64) {
                        slot_val[cc * 64 + pos] = sval[p];
                        slot_col[cc * 64 + pos] = (unsigned short)c;
                        break;
                    }
                }
                ++k;
            }
        }
    }
    __syncthreads();

    float* vrow = vals + (size_t)r * KSLOTS;
    unsigned short* crow = cols + (size_t)r * KSLOTS;
    for (int j = tid; j < KSLOTS; j += blockDim.x) { vrow[j] = slot_val[j]; crow[j] = slot_col[j]; }
}

// ---------------------------------------------------------------------------
// Coherent 16B load straight from the coherence point (bypasses L1+L2).
// R4-proven (passed full harness incl. replay tripwires).
// ---------------------------------------------------------------------------
__device__ __forceinline__ f32x4 load_coherent_x4(const float* p) {
    f32x4 v;
    asm volatile("global_load_dwordx4 %0, %1, off sc0 sc1\n\t"
                 "s_waitcnt vmcnt(0)"
                 : "=v"(v) : "v"(p) : "memory");
    return v;
}

// Branch-free tanh: tanh(|v|) = 1 - 2/(exp2(2*log2e*|v|)+1), sign restored
// via copysign. Numerically validated in R6's first launch (absmax 3.9e-3,
// identical to libm tanhf). Value-local: cannot affect synchronization.
__device__ __forceinline__ float fast_tanh(float v) {
    float ax = __builtin_fabsf(v);
    float e  = __builtin_amdgcn_exp2f(ax * 2.88539008177793f);  // 2*log2(e)
    float r  = 1.0f - 2.0f * __builtin_amdgcn_rcpf(e + 1.0f);
    return __builtin_copysignf(r, v);
}

// ---------------------------------------------------------------------------
// Kernel 2: persistent step kernel — EXACT R4 structure (the best verified
// configuration: 256 blocks x 1024 threads, 1 row/wave, single h buffer,
// TWO barriers/step, s_sleep(1) poll, data-as-flag sentinel, write-through
// producer stores). Sole change vs R4: tanhf -> fast_tanh.
//  - ELL slice register-hoisted: zero weight traffic in the t-loop.
//  - consumers poll out[t-1] with coherent dwordx4; skew self-limits at
//    1 step; each block writes only its own 16 rows.
// ---------------------------------------------------------------------------
__global__ void __launch_bounds__(NTHREADS, 1) esn_steps(
    const float* __restrict__ x,
    const float* __restrict__ W_in,
    const float* __restrict__ vals,
    const unsigned short* __restrict__ cols,
    float* __restrict__ out) {

    __shared__ float h_lds[N];       // full previous state, 16 KB
    __shared__ float x_lds[IN_DIM];

    const int tid  = threadIdx.x;
    const int lane = tid & 63;
    const int wave = tid >> 6;
    const int r    = blockIdx.x * WAVES_PER_BLOCK + wave;  // fixed row

    const float w0 = W_in[r * IN_DIM + lane];
    const float w1 = W_in[r * IN_DIM + 64 + lane];

    // Hoist this lane's ELL slice into registers (9 vals + 9 byte offsets).
    const float* __restrict__ vp = vals + (size_t)r * KSLOTS;
    const unsigned short* __restrict__ cp = cols + (size_t)r * KSLOTS;
    float rv[CHUNKS];
    int   rc[CHUNKS];
    #pragma unroll
    for (int i = 0; i < CHUNKS; ++i) {
        rv[i] = vp[(i << 6) + lane];
        rc[i] = ((int)cp[(i << 6) + lane]) << 2;
    }

    const int i4 = tid << 2;

    for (int t = 0; t < T_STEPS; ++t) {
        // ---- stage x_t (global load overlaps the poll below) ----
        if (tid < IN_DIM) x_lds[tid] = x[t * IN_DIM + tid];

        // ---- stage h_{t-1}: coherent dwordx4 poll until sentinel gone ----
        f32x4 hv;
        if (t > 0) {
            const float* addr = out + (size_t)(t - 1) * N + i4;
            for (;;) {
                hv = load_coherent_x4(addr);
                bool not_ready = (__float_as_uint(hv.x) == SENTINEL_BITS) |
                                 (__float_as_uint(hv.y) == SENTINEL_BITS) |
                                 (__float_as_uint(hv.z) == SENTINEL_BITS) |
                                 (__float_as_uint(hv.w) == SENTINEL_BITS);
                if (!not_ready) break;
                __builtin_amdgcn_s_sleep(1);
            }
        } else {
            hv = (f32x4)(0.0f);
        }
        ((f32x4*)h_lds)[tid] = hv;
        __syncthreads();   // barrier 1: h_lds fully staged

        // ---- row dot: input part + register-ELL sparse gather ----
        float acc = w0 * x_lds[lane] + w1 * x_lds[64 + lane];
        #pragma unroll
        for (int i = 0; i < CHUNKS; ++i) {
            acc += rv[i] * *(const float*)((const char*)h_lds + rc[i]);
        }
        #pragma unroll
        for (int off = 32; off > 0; off >>= 1) acc += __shfl_xor(acc, off);

        if (lane == 0) {
            float hp = h_lds[r];
            float hn = 0.7f * hp + 0.3f * fast_tanh(acc);
            // write-through: visible at the coherence point to all pollers
            __hip_atomic_store(&out[(size_t)t * N + r], hn,
                               __ATOMIC_RELAXED, __HIP_MEMORY_SCOPE_AGENT);
        }
        __syncthreads();   // barrier 2: all h_lds reads done before next stage
    }
}

// ---------------------------------------------------------------------------
// Workspace layout (bytes):
//   [0, +N*KSLOTS*4)       ELL vals (f32)   9.44 MB
//   [.., +N*KSLOTS*2)      ELL cols (u16)   4.72 MB
// ---------------------------------------------------------------------------
extern "C" void kernel_launch(void* const* d_in, const int* in_sizes, int n_in,
                              void* d_out, int out_size, void* d_ws, size_t ws_size,
                              hipStream_t stream) {
    const float* x    = (const float*)d_in[0];  // [2048,128]
    const float* W_in = (const float*)d_in[1];  // [4096,128]
    const float* W    = (const float*)d_in[2];  // [4096,4096]
    float* out = (float*)d_out;                 // [2048,4096]

    char* ws = (char*)d_ws;
    float* vals = (float*)ws;
    unsigned short* cols = (unsigned short*)(ws + (size_t)N * KSLOTS * 4);

    init_sentinel<<<(T_STEPS * N) / NTHREADS, NTHREADS, 0, stream>>>(out);
    build_ell<<<N, 256, 0, stream>>>(W, vals, cols);

    void* args[] = {(void*)&x, (void*)&W_in, (void*)&vals, (void*)&cols, (void*)&out};
    hipLaunchCooperativeKernel((void*)esn_steps, dim3(NBLOCKS), dim3(NTHREADS),
                               args, 0, stream);
}

// Round 11
// 6521.676 us; speedup vs baseline: 1.2673x; 1.1634x over previous
//
#include <hip/hip_runtime.h>

#define N 4096
#define IN_DIM 128
#define T_STEPS 2048
#define KSLOTS 576           // uniform padded ELL row width; max nnz ~490 (mean 409.6, sd 19.2)
#define CHUNKS (KSLOTS / 64) // 9, uniform for all rows
#define NBLOCKS 128
#define NTHREADS 1024
#define ROWS_PER_WAVE 2
#define ROWS_PER_BLOCK (ROWS_PER_WAVE * (NTHREADS / 64))   // 32
#define SENTINEL_BITS 0x7FC00001u   // qNaN; h is always finite -> producers never write this

typedef float f32x4 __attribute__((ext_vector_type(4)));

// ---------------------------------------------------------------------------
// Kernel 0: fill out with the sentinel, write-through (agent scope) so it is
// at the coherence point before any step-kernel poll. Defends against 0xAA
// poison and stale floats from a previous replay (both non-sentinel).
// ---------------------------------------------------------------------------
__global__ void init_sentinel(float* __restrict__ out) {
    const size_t i = (size_t)blockIdx.x * blockDim.x + threadIdx.x;
    __hip_atomic_store(&out[i], __uint_as_float(SENTINEL_BITS),
                       __ATOMIC_RELAXED, __HIP_MEMORY_SCOPE_AGENT);
}

// ---------------------------------------------------------------------------
// Kernel 1: dense W -> uniform padded ELL with bank-aware chunk assignment
// (each 64-slot chunk hits every LDS bank ~2x; 2-way is free on gfx950).
// Padding: val=0, col=0 (same-address broadcast, free). Unchanged since R2.
// ---------------------------------------------------------------------------
__global__ void build_ell(const float* __restrict__ W,
                          float* __restrict__ vals,
                          unsigned short* __restrict__ cols) {
    __shared__ float sval[KSLOTS];
    __shared__ unsigned short scol[KSLOTS];
    __shared__ float slot_val[KSLOTS];
    __shared__ unsigned short slot_col[KSLOTS];
    __shared__ int chunk_fill[CHUNKS];
    __shared__ int cnt;

    const int r = blockIdx.x;
    const int tid = threadIdx.x;
    if (tid == 0) cnt = 0;
    if (tid < CHUNKS) chunk_fill[tid] = 0;
    __syncthreads();

    const float* wrow = W + (size_t)r * N;
    for (int j = tid; j < N; j += blockDim.x) {
        float w = wrow[j];
        if (w != 0.0f) {
            int p = atomicAdd(&cnt, 1);
            if (p < KSLOTS) { sval[p] = w; scol[p] = (unsigned short)j; }
        }
    }
    __syncthreads();
    for (int j = tid; j < KSLOTS; j += blockDim.x) { slot_val[j] = 0.0f; slot_col[j] = 0; }
    __syncthreads();

    if (tid < 32) {  // one thread per bank spreads its entries across chunks
        int k = 0;
        const int n = (cnt < KSLOTS) ? cnt : KSLOTS;
        for (int p = 0; p < n; ++p) {
            int c = scol[p];
            if ((c & 31) == tid) {
                int ch0 = (k + tid) % CHUNKS;
                for (int probe = 0; probe < CHUNKS; ++probe) {
                    int cc = ch0 + probe; if (cc >= CHUNKS) cc -= CHUNKS;
                    int pos = atomicAdd(&chunk_fill[cc], 1);
                    if (pos < 64) {
                        slot_val[cc * 64 + pos] = sval[p];
                        slot_col[cc * 64 + pos] = (unsigned short)c;
                        break;
                    }
                }
                ++k;
            }
        }
    }
    __syncthreads();

    float* vrow = vals + (size_t)r * KSLOTS;
    unsigned short* crow = cols + (size_t)r * KSLOTS;
    for (int j = tid; j < KSLOTS; j += blockDim.x) { vrow[j] = slot_val[j]; crow[j] = slot_col[j]; }
}

// ---------------------------------------------------------------------------
// Coherent 16B load straight from the coherence point (bypasses L1+L2).
// R4/R9-proven (passed full harness incl. replay tripwires).
// ---------------------------------------------------------------------------
__device__ __forceinline__ f32x4 load_coherent_x4(const float* p) {
    f32x4 v;
    asm volatile("global_load_dwordx4 %0, %1, off sc0 sc1\n\t"
                 "s_waitcnt vmcnt(0)"
                 : "=v"(v) : "v"(p) : "memory");
    return v;
}

// Branch-free tanh (validated R6-first-launch + R9: absmax 3.9e-3 unchanged).
__device__ __forceinline__ float fast_tanh(float v) {
    float ax = __builtin_fabsf(v);
    float e  = __builtin_amdgcn_exp2f(ax * 2.88539008177793f);  // 2*log2(e)
    float r  = 1.0f - 2.0f * __builtin_amdgcn_rcpf(e + 1.0f);
    return __builtin_copysignf(r, v);
}

// ---------------------------------------------------------------------------
// Kernel 2: persistent step kernel — R9's proven skeleton (single h buffer,
// TWO barriers/step, s_sleep(1) poll, data-as-flag sentinel, write-through
// producer stores). A/B variable vs R9: NBLOCKS 256->128, 2 rows/wave.
// This halves poll/broadcast transactions at the coherence point while
// keeping every synchronization mechanism byte-identical.
// ---------------------------------------------------------------------------
__global__ void __launch_bounds__(NTHREADS, 1) esn_steps(
    const float* __restrict__ x,
    const float* __restrict__ W_in,
    const float* __restrict__ vals,
    const unsigned short* __restrict__ cols,
    float* __restrict__ out) {

    __shared__ float h_lds[N];       // full previous state, 16 KB
    __shared__ float x_lds[IN_DIM];

    const int tid  = threadIdx.x;
    const int lane = tid & 63;
    const int wave = tid >> 6;
    const int base = blockIdx.x * ROWS_PER_BLOCK + wave * ROWS_PER_WAVE;  // 2 rows/wave

    // Per-row W_in slices.
    float w0[ROWS_PER_WAVE], w1[ROWS_PER_WAVE];
    #pragma unroll
    for (int j = 0; j < ROWS_PER_WAVE; ++j) {
        w0[j] = W_in[(base + j) * IN_DIM + lane];
        w1[j] = W_in[(base + j) * IN_DIM + 64 + lane];
    }

    // Hoist the 2-row ELL slice into registers (18 vals + 18 byte offsets).
    float rv[ROWS_PER_WAVE][CHUNKS];
    int   rc[ROWS_PER_WAVE][CHUNKS];
    #pragma unroll
    for (int j = 0; j < ROWS_PER_WAVE; ++j) {
        const float* vp = vals + (size_t)(base + j) * KSLOTS;
        const unsigned short* cp = cols + (size_t)(base + j) * KSLOTS;
        #pragma unroll
        for (int i = 0; i < CHUNKS; ++i) {
            rv[j][i] = vp[(i << 6) + lane];
            rc[j][i] = ((int)cp[(i << 6) + lane]) << 2;
        }
    }

    const int i4 = tid << 2;

    for (int t = 0; t < T_STEPS; ++t) {
        // ---- stage x_t (global load overlaps the poll below) ----
        if (tid < IN_DIM) x_lds[tid] = x[t * IN_DIM + tid];

        // ---- stage h_{t-1}: coherent dwordx4 poll until sentinel gone ----
        f32x4 hv;
        if (t > 0) {
            const float* addr = out + (size_t)(t - 1) * N + i4;
            for (;;) {
                hv = load_coherent_x4(addr);
                bool not_ready = (__float_as_uint(hv.x) == SENTINEL_BITS) |
                                 (__float_as_uint(hv.y) == SENTINEL_BITS) |
                                 (__float_as_uint(hv.z) == SENTINEL_BITS) |
                                 (__float_as_uint(hv.w) == SENTINEL_BITS);
                if (!not_ready) break;
                __builtin_amdgcn_s_sleep(1);
            }
        } else {
            hv = (f32x4)(0.0f);
        }
        ((f32x4*)h_lds)[tid] = hv;
        __syncthreads();   // barrier 1: h_lds fully staged

        // ---- 2 row dots: input part + register-ELL sparse gather ----
        float acc[ROWS_PER_WAVE];
        const float xa = x_lds[lane], xb = x_lds[64 + lane];
        #pragma unroll
        for (int j = 0; j < ROWS_PER_WAVE; ++j) acc[j] = w0[j] * xa + w1[j] * xb;

        #pragma unroll
        for (int j = 0; j < ROWS_PER_WAVE; ++j) {
            #pragma unroll
            for (int i = 0; i < CHUNKS; ++i) {
                acc[j] += rv[j][i] * *(const float*)((const char*)h_lds + rc[j][i]);
            }
        }

        // butterfly reduce each acc[j] across the wave
        #pragma unroll
        for (int j = 0; j < ROWS_PER_WAVE; ++j) {
            #pragma unroll
            for (int off = 32; off > 0; off >>= 1)
                acc[j] += __shfl_xor(acc[j], off);
        }

        // lanes 0..1 finalize + store one row each (same proven store path)
        if (lane < ROWS_PER_WAVE) {
            float a = (lane == 0) ? acc[0] : acc[1];
            float hp = h_lds[base + lane];
            float hn = 0.7f * hp + 0.3f * fast_tanh(a);
            __hip_atomic_store(&out[(size_t)t * N + base + lane], hn,
                               __ATOMIC_RELAXED, __HIP_MEMORY_SCOPE_AGENT);
        }
        __syncthreads();   // barrier 2: all h_lds reads done before next stage
    }
}

// ---------------------------------------------------------------------------
// Workspace layout (bytes):
//   [0, +N*KSLOTS*4)       ELL vals (f32)   9.44 MB
//   [.., +N*KSLOTS*2)      ELL cols (u16)   4.72 MB
// ---------------------------------------------------------------------------
extern "C" void kernel_launch(void* const* d_in, const int* in_sizes, int n_in,
                              void* d_out, int out_size, void* d_ws, size_t ws_size,
                              hipStream_t stream) {
    const float* x    = (const float*)d_in[0];  // [2048,128]
    const float* W_in = (const float*)d_in[1];  // [4096,128]
    const float* W    = (const float*)d_in[2];  // [4096,4096]
    float* out = (float*)d_out;                 // [2048,4096]

    char* ws = (char*)d_ws;
    float* vals = (float*)ws;
    unsigned short* cols = (unsigned short*)(ws + (size_t)N * KSLOTS * 4);

    init_sentinel<<<(T_STEPS * N) / NTHREADS, NTHREADS, 0, stream>>>(out);
    build_ell<<<N, 256, 0, stream>>>(W, vals, cols);

    void* args[] = {(void*)&x, (void*)&W_in, (void*)&vals, (void*)&cols, (void*)&out};
    hipLaunchCooperativeKernel((void*)esn_steps, dim3(NBLOCKS), dim3(NTHREADS),
                               args, 0, stream);
}